// Round 2
// baseline (556.842 us; speedup 1.0000x reference)
//
#include <hip/hip_runtime.h>
#include <cstdint>

// Shapes (fixed by reference): b=4,h=8 -> 32 heads; n=2048; nc=1024; d=K=512.
#define NC    1024
#define D     512
#define KTOT  512
#define MTOT  32768       // 32 heads * NC

typedef short  short8  __attribute__((ext_vector_type(8)));   // 8 x bf16
typedef float  floatx4 __attribute__((ext_vector_type(4)));

__device__ inline unsigned short f2bf_rne(float f) {
  union { float f; unsigned u; } x; x.f = f;
  unsigned r = x.u + 0x7fffu + ((x.u >> 16) & 1u);
  return (unsigned short)(r >> 16);
}

__device__ inline float bf2f(unsigned short u) {
  union { unsigned u; float f; } x; x.u = ((unsigned)u) << 16; return x.f;
}

__global__ __launch_bounds__(256) void cvt_f32_bf16(
    const float* __restrict__ src, unsigned short* __restrict__ dst, int n4) {
  int i = blockIdx.x * 256 + threadIdx.x;
  if (i >= n4) return;
  float4 v = ((const float4*)src)[i];
  ushort4 o;
  o.x = f2bf_rne(v.x); o.y = f2bf_rne(v.y);
  o.z = f2bf_rne(v.z); o.w = f2bf_rne(v.w);
  ((ushort4*)dst)[i] = o;
}

// LDS-free, barrier-free fused GEMM.
// Block = 128 rows x 64 out-cols. 4 waves in 2x2: wave (wr,wc) owns
// rows [wr*64, wr*64+64) (rt=0..3 of 16) and cols [wc*32, wc*32+32)
// (csub=0..1 of 16), for all three beta blocks of W:
//   P0 = u_j.W0^T, P1 = u_j.W1^T, P2s = u_{j+1}.W2^T  (A at +1 row via
//   +1024B immediate offset; head-boundary lane zeroed).
// A/B fragments are loaded directly global->VGPR: a wave's fragment touches
// 16 rows x 64B with every cache line fully consumed (quad covers k), so
// coalescing is line-perfect. No __shared__, no __syncthreads.
__global__ __launch_bounds__(256, 3) void fused_uncompress_gemm(
    const unsigned short* __restrict__ Ub,   // (32768, 512) bf16
    const unsigned short* __restrict__ Wb,   // (512, 1536) bf16 row-major W
    const float* __restrict__ LQ,            // (32, 2048, 512) f32
    const float* __restrict__ bias,          // (512) f32
    float* __restrict__ out)                 // (32, 2048, 512) f32
{
  const int tileM = blockIdx.x >> 3;
  const int tileN = blockIdx.x & 7;
  const int r0 = tileM * 128;
  const int n0 = tileN * 64;
  const int tid  = threadIdx.x;
  const int wv   = tid >> 6;
  const int ln   = tid & 63;
  const int wr   = wv >> 1;          // row half
  const int wc   = wv & 1;           // col half
  const int quad = ln >> 4;
  const int am   = ln & 15;

  // A fragment base addresses, one per rt (rt*16 rows = 16KB stride exceeds
  // the 13-bit immediate, so 4 base pointers; k-stream + a1(+1024B) via imm).
  const short8* aPtr[4];
  bool zeroA1[4];
  #pragma unroll
  for (int rt = 0; rt < 4; ++rt) {
    int row = r0 + wr * 64 + rt * 16 + am;
    aPtr[rt] = (const short8*)(Ub + (size_t)row * KTOT + quad * 8);
    zeroA1[rt] = (((row + 1) & (NC - 1)) == 0);   // u_{j+1} := 0 at head end
  }
  // B fragment bases, one per col-subtile (beta*1024B + k via imm, max 3008B).
  const short8* bPtr[2];
  #pragma unroll
  for (int c = 0; c < 2; ++c) {
    int brow = n0 + wc * 32 + c * 16 + am;
    bPtr[c] = (const short8*)(Wb + (size_t)brow * 1536 + quad * 8);
  }

  floatx4 acc[4][6];   // [rt][beta*2 + csub]
  #pragma unroll
  for (int rt = 0; rt < 4; ++rt)
    #pragma unroll
    for (int ct = 0; ct < 6; ++ct)
      acc[rt][ct] = floatx4{0.f, 0.f, 0.f, 0.f};

  #pragma unroll
  for (int kc = 0; kc < 16; ++kc) {            // 16 steps of K=32
    const int ko = kc * 4;                     // in short8 units (32 elems)
    short8 a0[4], a1[4];
    #pragma unroll
    for (int rt = 0; rt < 4; ++rt) {
      a0[rt] = aPtr[rt][ko];
      short8 t = aPtr[rt][ko + 64];            // +512 elems = row+1
      if (zeroA1[rt]) t = (short8)0;
      a1[rt] = t;
    }
    short8 b[6];
    #pragma unroll
    for (int ct = 0; ct < 6; ++ct) {
      int beta = ct >> 1, c = ct & 1;
      b[ct] = bPtr[c][ko + beta * 64];         // +beta*512 elems
    }
    #pragma unroll
    for (int ct = 0; ct < 6; ++ct) {
      int beta = ct >> 1;
      #pragma unroll
      for (int rt = 0; rt < 4; ++rt) {
        acc[rt][ct] = __builtin_amdgcn_mfma_f32_16x16x32_bf16(
            (beta == 2) ? a1[rt] : a0[rt], b[ct], acc[rt][ct], 0, 0, 0);
      }
    }
  }

  // Epilogue. C/D map: col = lane&15, row = quad*4 + reg (verified m89/m91).
  const float inv3 = 1.0f / 3.0f;
  #pragma unroll
  for (int csub = 0; csub < 2; ++csub) {
    int col = n0 + wc * 32 + csub * 16 + am;
    float bv = bias[col];
    #pragma unroll
    for (int rt = 0; rt < 4; ++rt) {
      #pragma unroll
      for (int r = 0; r < 4; ++r) {
        int j  = r0 + wr * 64 + rt * 16 + quad * 4 + r;
        int head = j >> 10;
        int jn   = j & (NC - 1);
        size_t ob = ((size_t)head * 2048 + 2 * jn) * D + col;
        float p0 = acc[rt][0 + csub][r];
        float p1 = acc[rt][2 + csub][r];
        float p2 = acc[rt][4 + csub][r];
        float uj  = bf2f(Ub[(size_t)j * D + col]);
        float uj1 = (jn == NC - 1) ? 0.f : bf2f(Ub[(size_t)(j + 1) * D + col]);
        float e = fmaxf(p1 + bv, 0.f);
        float o = fmaxf(p0 + p2 + bv, 0.f);
        out[ob]     = LQ[ob]     + e + uj * inv3;
        out[ob + D] = LQ[ob + D] + o + (uj + uj1) * inv3;
      }
    }
  }
}

extern "C" void kernel_launch(void* const* d_in, const int* in_sizes, int n_in,
                              void* d_out, int out_size, void* d_ws, size_t ws_size,
                              hipStream_t stream) {
  const float* LQ   = (const float*)d_in[0];   // (4,8,2048,512)
  const float* U32  = (const float*)d_in[1];   // (4,8,1024,512)
  const float* W    = (const float*)d_in[2];   // (512, 1536)
  const float* bias = (const float*)d_in[3];   // (512)
  float* out = (float*)d_out;

  unsigned short* Ub = (unsigned short*)d_ws;                         // 33.5 MB
  unsigned short* Wb = (unsigned short*)((char*)d_ws + (size_t)MTOT * KTOT * 2);

  const int n4U = MTOT * KTOT / 4;     // 4,194,304
  const int n4W = 512 * 1536 / 4;      // 196,608
  cvt_f32_bf16<<<(n4U + 255) / 256, 256, 0, stream>>>(U32, Ub, n4U);
  cvt_f32_bf16<<<(n4W + 255) / 256, 256, 0, stream>>>(W, Wb, n4W);

  // 256 M-tiles x 8 N-tiles; consecutive blocks share an M-tile (L2/L3 reuse).
  fused_uncompress_gemm<<<dim3(2048), dim3(256), 0, stream>>>(
      Ub, Wb, LQ, bias, out);
}